// Round 10
// baseline (182.461 us; speedup 1.0000x reference)
//
#include <hip/hip_runtime.h>
#include <math.h>

#define N_NODES 60000
#define M1_N    40000
#define M2_N    40000
#define DD      64
#define S0_N    10
#define S1_N    20
#define R_TOTAL (N_NODES + M1_N + M2_N)
#define T_H0    (N_NODES / 16)              // 3750 tiles
#define T_H1    (T_H0 + M1_N / 16)          // 6250
#define T_ALL   (T_H1 + M2_N / 16)          // 8750
#define PROJ_GRID 2048                      // must equal k_proj launch grid
#define BETA_GRID 512                       // must equal k_beta launch grid

typedef __attribute__((ext_vector_type(8))) short short8;   // 8 bf16 = 4 VGPRs
typedef __attribute__((ext_vector_type(4))) float f32x4;

__device__ __forceinline__ float wave_sum(float x) {
#pragma unroll
    for (int o = 32; o >= 1; o >>= 1) x += __shfl_xor(x, o, 64);
    return x;
}
__device__ __forceinline__ float bcast(float v, int l) {
    return __uint_as_float(__builtin_amdgcn_readlane(__float_as_uint(v), l));
}
__device__ __forceinline__ float tanh_fast(float x) {
    return 1.f - 2.f / (__expf(2.f * x) + 1.f);
}
// f32 -> bf16 round-to-nearest-even
__device__ __forceinline__ unsigned short f2bf(float x) {
    unsigned u = __float_as_uint(x);
    return (unsigned short)((u + 0x7FFFu + ((u >> 16) & 1u)) >> 16);
}
__device__ __forceinline__ float bf2f(unsigned short u) {
    return __uint_as_float(((unsigned)u) << 16);
}
__device__ __forceinline__ float elu(float x) {
    return (x > 0.f) ? x : (__expf(x) - 1.f);
}

// Kernel 1: projections + global softmax via MFMA (unchanged from round 9).
__global__ __launch_bounds__(256) void k_proj(
    const float* __restrict__ h0, const float* __restrict__ h1, const float* __restrict__ h2,
    const float* __restrict__ aw0, const float* __restrict__ aw1, const float* __restrict__ gatt,
    float* __restrict__ part,
    float* __restrict__ p0r0, float* __restrict__ p0r1,
    float* __restrict__ p1, float* __restrict__ p2,
    unsigned short* __restrict__ h1bf, unsigned short* __restrict__ h2bf)
{
    __shared__ float s_wsum[64];
    __shared__ float s_se;
    const int tid = threadIdx.x, lane = tid & 63, wid = tid >> 6;
    if (tid < 64) s_wsum[tid] = 0.f;
    if (tid == 0) s_se = 0.f;
    __syncthreads();

    const int m = lane & 15, quad = lane >> 4;

    short8 b0, b1;
    {
        const float* vsel = 0;
        if (m == 1) vsel = aw0;
        else if (m == 2) vsel = aw1;
        else if (m == 3) vsel = aw0 + DD;
        else if (m == 4) vsel = aw1 + DD;
        else if (m == 0) vsel = gatt;
#pragma unroll
        for (int j = 0; j < 8; j++) {
            b0[j] = vsel ? (short)f2bf(vsel[quad * 8 + j]) : (short)0;
            b1[j] = vsel ? (short)f2bf(vsel[32 + quad * 8 + j]) : (short)0;
        }
    }

    float wacc0[8], wacc1[8];
#pragma unroll
    for (int j = 0; j < 8; j++) { wacc0[j] = 0.f; wacc1[j] = 0.f; }
    float r_se = 0.f;

    const int srcl = (m >> 2) << 4;     // lane holding col-0 scores for my row
    const int rsel = m & 3;

    const int gw = blockIdx.x * 4 + wid, nw = gridDim.x * 4;
    for (int tile = gw; tile < T_ALL; tile += nw) {
        const float* src; int rbase, region;
        if (tile < T_H0)      { src = h0; rbase = tile * 16;          region = 0; }
        else if (tile < T_H1) { src = h1; rbase = (tile - T_H0) * 16; region = 1; }
        else                  { src = h2; rbase = (tile - T_H1) * 16; region = 2; }
        const int row = rbase + m;
        const float4* rpa = (const float4*)(src + (size_t)row * DD + quad * 8);
        const float4* rpb = (const float4*)(src + (size_t)row * DD + 32 + quad * 8);
        const float4 va = rpa[0], vb = rpa[1];
        const float4 vc = rpb[0], vd = rpb[1];

        short8 a0, a1;
        a0[0] = (short)f2bf(va.x); a0[1] = (short)f2bf(va.y);
        a0[2] = (short)f2bf(va.z); a0[3] = (short)f2bf(va.w);
        a0[4] = (short)f2bf(vb.x); a0[5] = (short)f2bf(vb.y);
        a0[6] = (short)f2bf(vb.z); a0[7] = (short)f2bf(vb.w);
        a1[0] = (short)f2bf(vc.x); a1[1] = (short)f2bf(vc.y);
        a1[2] = (short)f2bf(vc.z); a1[3] = (short)f2bf(vc.w);
        a1[4] = (short)f2bf(vd.x); a1[5] = (short)f2bf(vd.y);
        a1[6] = (short)f2bf(vd.z); a1[7] = (short)f2bf(vd.w);

        f32x4 c = {0.f, 0.f, 0.f, 0.f};
        c = __builtin_amdgcn_mfma_f32_16x16x32_bf16(a0, b0, c, 0, 0, 0);
        c = __builtin_amdgcn_mfma_f32_16x16x32_bf16(a1, b1, c, 0, 0, 0);

        const float t0 = __shfl(c[0], srcl, 64);
        const float t1 = __shfl(c[1], srcl, 64);
        const float t2 = __shfl(c[2], srcl, 64);
        const float t3 = __shfl(c[3], srcl, 64);
        const float scr = (rsel == 0) ? t0 : (rsel == 1) ? t1 : (rsel == 2) ? t2 : t3;
        const float es = __expf(scr * 0.125f);
        r_se += es;
        wacc0[0] = fmaf(es, va.x, wacc0[0]); wacc0[1] = fmaf(es, va.y, wacc0[1]);
        wacc0[2] = fmaf(es, va.z, wacc0[2]); wacc0[3] = fmaf(es, va.w, wacc0[3]);
        wacc0[4] = fmaf(es, vb.x, wacc0[4]); wacc0[5] = fmaf(es, vb.y, wacc0[5]);
        wacc0[6] = fmaf(es, vb.z, wacc0[6]); wacc0[7] = fmaf(es, vb.w, wacc0[7]);
        wacc1[0] = fmaf(es, vc.x, wacc1[0]); wacc1[1] = fmaf(es, vc.y, wacc1[1]);
        wacc1[2] = fmaf(es, vc.z, wacc1[2]); wacc1[3] = fmaf(es, vc.w, wacc1[3]);
        wacc1[4] = fmaf(es, vd.x, wacc1[4]); wacc1[5] = fmaf(es, vd.y, wacc1[5]);
        wacc1[6] = fmaf(es, vd.z, wacc1[6]); wacc1[7] = fmaf(es, vd.w, wacc1[7]);

        if (region == 0) {
            if (m == 1) { float4 t = {c[0], c[1], c[2], c[3]}; *(float4*)(p0r0 + rbase + quad * 4) = t; }
            if (m == 2) { float4 t = {c[0], c[1], c[2], c[3]}; *(float4*)(p0r1 + rbase + quad * 4) = t; }
        } else if (region == 1) {
            if (m == 3) { float4 t = {c[0], c[1], c[2], c[3]}; *(float4*)(p1 + rbase + quad * 4) = t; }
            *(short8*)(h1bf + (size_t)row * DD + quad * 8) = a0;
            *(short8*)(h1bf + (size_t)row * DD + 32 + quad * 8) = a1;
        } else {
            if (m == 4) { float4 t = {c[0], c[1], c[2], c[3]}; *(float4*)(p2 + rbase + quad * 4) = t; }
            *(short8*)(h2bf + (size_t)row * DD + quad * 8) = a0;
            *(short8*)(h2bf + (size_t)row * DD + 32 + quad * 8) = a1;
        }
    }

    r_se *= 0.25f;
#pragma unroll
    for (int o = 1; o <= 8; o <<= 1) {
#pragma unroll
        for (int j = 0; j < 8; j++) {
            wacc0[j] += __shfl_xor(wacc0[j], o, 64);
            wacc1[j] += __shfl_xor(wacc1[j], o, 64);
        }
    }
    if (m == 0) {
#pragma unroll
        for (int j = 0; j < 8; j++) {
            atomicAdd(&s_wsum[quad * 8 + j],      wacc0[j]);
            atomicAdd(&s_wsum[32 + quad * 8 + j], wacc1[j]);
        }
    }
    const float se = wave_sum(r_se);
    if (lane == 0) atomicAdd(&s_se, se);
    __syncthreads();
    if (tid < 64) part[tid * PROJ_GRID + blockIdx.x] = s_wsum[tid];
    if (tid == 64) part[64 * PROJ_GRID + blockIdx.x] = s_se;
}

// Kernel 2: neighbor attention, phase-split + 2-NODE PACKING + NT hints.
// Nodes (n, n+1) ride in half-waves: scores in lanes 0..S-1 / 32..32+S-1.
// Gather slots s=4j+grp interleave both nodes' rows (predicated accumulate).
// e stores are non-temporal (write-once) and nei loads non-temporal (stream)
// to keep L2 free for the 5.12 MB gather table (round-8: L2 thrash bound).
__global__ __launch_bounds__(256) void k_attn(
    const unsigned short* __restrict__ h1bf,
    const int* __restrict__ nei0, const int* __restrict__ nei1,
    const float* __restrict__ p0r0, const float* __restrict__ p0r1,
    const float* __restrict__ p1,
    unsigned short* __restrict__ e0bf, unsigned short* __restrict__ e1bf)
{
    const int tid = threadIdx.x, lane = tid & 63, wid = tid >> 6;
    const int sub = lane & 15, grp = lane >> 4;
    const int h = lane >> 5, hl = lane & 31;     // half-wave node select
    const int gw = blockIdx.x * 4 + wid;
    const int nw = gridDim.x * 4;

    // ---------------- phase A: e0 (10 neighbors/node, 2 nodes/iter) --------
    for (int n0 = gw * 2; n0 < N_NODES; n0 += nw * 2) {
        const int n = n0 + h;
        int idx = 0; float w = 0.f;
        if (hl < S0_N) {
            idx = __builtin_nontemporal_load(nei0 + n * S0_N + hl);
            float sc = p0r0[n] + p1[idx];
            sc = (sc >= 0.f) ? sc : 0.01f * sc;       // leaky_relu(0.01)
            w = __expf(sc);                            // bounded; no max-sub
        }
        // 20 slots: s = 4j+grp; s<10 -> node0 nbr s (lane s), else node1 (lane 22+s)
        int rows[5], srcs[5];
#pragma unroll
        for (int j = 0; j < 5; j++) {
            const int s = 4 * j + grp;
            srcs[j] = (s < S0_N) ? s : (32 - S0_N + s);
            rows[j] = __shfl(idx, srcs[j], 64);
        }
        ushort4 u[5];
#pragma unroll
        for (int j = 0; j < 5; j++)
            u[j] = *(const ushort4*)(h1bf + rows[j] * DD + 4 * sub);

        float sv = w;                                  // per-16-group sum
#pragma unroll
        for (int o = 8; o >= 1; o >>= 1) sv += __shfl_xor(sv, o, 64);
        const float invA = 1.f / bcast(sv, 0);
        const float invB = 1.f / bcast(sv, 32);

        float4 aA = make_float4(0.f, 0.f, 0.f, 0.f);
        float4 aB = make_float4(0.f, 0.f, 0.f, 0.f);
#pragma unroll
        for (int j = 0; j < 5; j++) {
            const float ws = __uint_as_float(
                (unsigned)__shfl(__float_as_int(w), srcs[j], 64));
            const bool isA = (4 * j + grp) < S0_N;
            float4 x;
            x.x = bf2f(u[j].x); x.y = bf2f(u[j].y);
            x.z = bf2f(u[j].z); x.w = bf2f(u[j].w);
            if (isA) {
                aA.x = fmaf(ws, x.x, aA.x); aA.y = fmaf(ws, x.y, aA.y);
                aA.z = fmaf(ws, x.z, aA.z); aA.w = fmaf(ws, x.w, aA.w);
            } else {
                aB.x = fmaf(ws, x.x, aB.x); aB.y = fmaf(ws, x.y, aB.y);
                aB.z = fmaf(ws, x.z, aB.z); aB.w = fmaf(ws, x.w, aB.w);
            }
        }
#pragma unroll
        for (int o = 16; o <= 32; o <<= 1) {
            aA.x += __shfl_xor(aA.x, o, 64); aA.y += __shfl_xor(aA.y, o, 64);
            aA.z += __shfl_xor(aA.z, o, 64); aA.w += __shfl_xor(aA.w, o, 64);
            aB.x += __shfl_xor(aB.x, o, 64); aB.y += __shfl_xor(aB.y, o, 64);
            aB.z += __shfl_xor(aB.z, o, 64); aB.w += __shfl_xor(aB.w, o, 64);
        }
        if (grp == 0) {
            ushort4 s;
            s.x = f2bf(elu(aA.x * invA)); s.y = f2bf(elu(aA.y * invA));
            s.z = f2bf(elu(aA.z * invA)); s.w = f2bf(elu(aA.w * invA));
            __builtin_nontemporal_store(*(unsigned long long*)&s,
                (unsigned long long*)(e0bf + n0 * DD + 4 * sub));
        } else if (grp == 1) {
            ushort4 s;
            s.x = f2bf(elu(aB.x * invB)); s.y = f2bf(elu(aB.y * invB));
            s.z = f2bf(elu(aB.z * invB)); s.w = f2bf(elu(aB.w * invB));
            __builtin_nontemporal_store(*(unsigned long long*)&s,
                (unsigned long long*)(e0bf + (n0 + 1) * DD + 4 * sub));
        }
    }

    // ---------------- phase B: e1 (20 neighbors/node, 2 nodes/iter) --------
    for (int n0 = gw * 2; n0 < N_NODES; n0 += nw * 2) {
        const int n = n0 + h;
        int idx = 0; float w = 0.f;
        if (hl < S1_N) {
            idx = __builtin_nontemporal_load(nei1 + n * S1_N + hl) + M1_N;
            float sc = p0r1[n] + p1[idx];
            sc = (sc >= 0.f) ? sc : 0.01f * sc;
            w = __expf(sc);
        }
        // 40 slots: s = 4j+grp; s<20 -> node0 (lane s), else node1 (lane 12+s)
        int rows[10], srcs[10];
#pragma unroll
        for (int j = 0; j < 10; j++) {
            const int s = 4 * j + grp;
            srcs[j] = (s < S1_N) ? s : (32 - S1_N + s);
            rows[j] = __shfl(idx, srcs[j], 64);
        }
        ushort4 u[10];
#pragma unroll
        for (int j = 0; j < 10; j++)
            u[j] = *(const ushort4*)(h1bf + rows[j] * DD + 4 * sub);

        float sv = w;                                  // per-32-half sum
#pragma unroll
        for (int o = 16; o >= 1; o >>= 1) sv += __shfl_xor(sv, o, 64);
        const float invA = 1.f / bcast(sv, 0);
        const float invB = 1.f / bcast(sv, 32);

        float4 aA = make_float4(0.f, 0.f, 0.f, 0.f);
        float4 aB = make_float4(0.f, 0.f, 0.f, 0.f);
#pragma unroll
        for (int j = 0; j < 10; j++) {
            const float ws = __uint_as_float(
                (unsigned)__shfl(__float_as_int(w), srcs[j], 64));
            const bool isA = (4 * j + grp) < S1_N;
            float4 x;
            x.x = bf2f(u[j].x); x.y = bf2f(u[j].y);
            x.z = bf2f(u[j].z); x.w = bf2f(u[j].w);
            if (isA) {
                aA.x = fmaf(ws, x.x, aA.x); aA.y = fmaf(ws, x.y, aA.y);
                aA.z = fmaf(ws, x.z, aA.z); aA.w = fmaf(ws, x.w, aA.w);
            } else {
                aB.x = fmaf(ws, x.x, aB.x); aB.y = fmaf(ws, x.y, aB.y);
                aB.z = fmaf(ws, x.z, aB.z); aB.w = fmaf(ws, x.w, aB.w);
            }
        }
#pragma unroll
        for (int o = 16; o <= 32; o <<= 1) {
            aA.x += __shfl_xor(aA.x, o, 64); aA.y += __shfl_xor(aA.y, o, 64);
            aA.z += __shfl_xor(aA.z, o, 64); aA.w += __shfl_xor(aA.w, o, 64);
            aB.x += __shfl_xor(aB.x, o, 64); aB.y += __shfl_xor(aB.y, o, 64);
            aB.z += __shfl_xor(aB.z, o, 64); aB.w += __shfl_xor(aB.w, o, 64);
        }
        if (grp == 0) {
            ushort4 s;
            s.x = f2bf(elu(aA.x * invA)); s.y = f2bf(elu(aA.y * invA));
            s.z = f2bf(elu(aA.z * invA)); s.w = f2bf(elu(aA.w * invA));
            __builtin_nontemporal_store(*(unsigned long long*)&s,
                (unsigned long long*)(e1bf + n0 * DD + 4 * sub));
        } else if (grp == 1) {
            ushort4 s;
            s.x = f2bf(elu(aB.x * invB)); s.y = f2bf(elu(aB.y * invB));
            s.z = f2bf(elu(aB.z * invB)); s.w = f2bf(elu(aB.w * invB));
            __builtin_nontemporal_store(*(unsigned long long*)&s,
                (unsigned long long*)(e1bf + (n0 + 1) * DD + 4 * sub));
        }
    }
}

// Kernel 3: beta reduction via MFMA; per-block partial stores.
__global__ __launch_bounds__(256) void k_beta(
    const unsigned short* __restrict__ e0bf, const unsigned short* __restrict__ e1bf,
    const float* __restrict__ fcw, const float* __restrict__ fcb,
    const float* __restrict__ fus, float* __restrict__ bpart)
{
    __shared__ float s_part[2];
    const int tid = threadIdx.x, lane = tid & 63, wid = tid >> 6;
    if (tid < 2) s_part[tid] = 0.f;
    const int m = lane & 15, q = lane >> 4;

    short8 bfr[4][2];
    float fb[4], fu[4];
#pragma unroll
    for (int t = 0; t < 4; t++) {
        const float* wrow = fcw + (t * 16 + m) * DD;
#pragma unroll
        for (int hh = 0; hh < 2; hh++) {
            const float* p = wrow + hh * 32 + q * 8;
#pragma unroll
            for (int j = 0; j < 8; j++) bfr[t][hh][j] = (short)f2bf(p[j]);
        }
        fb[t] = fcb[t * 16 + m];
        fu[t] = fus[t * 16 + m];
    }
    __syncthreads();

    float rb0 = 0.f, rb1 = 0.f;
    const int gw = blockIdx.x * 4 + wid;
    const int nw = gridDim.x * 4;
    for (int tile = gw; tile < N_NODES / 16; tile += nw) {
        const int rowbase = (tile * 16 + m) * DD + q * 8;
        {
            const short8 a0 = *(const short8*)(e0bf + rowbase);
            const short8 a1 = *(const short8*)(e0bf + rowbase + 32);
            f32x4 c[4];
#pragma unroll
            for (int t = 0; t < 4; t++) {
                c[t] = f32x4{0.f, 0.f, 0.f, 0.f};
                c[t] = __builtin_amdgcn_mfma_f32_16x16x32_bf16(a0, bfr[t][0], c[t], 0, 0, 0);
                c[t] = __builtin_amdgcn_mfma_f32_16x16x32_bf16(a1, bfr[t][1], c[t], 0, 0, 0);
            }
#pragma unroll
            for (int t = 0; t < 4; t++)
#pragma unroll
                for (int j = 0; j < 4; j++)
                    rb0 += tanh_fast(c[t][j] + fb[t]) * fu[t];
        }
        {
            const short8 a0 = *(const short8*)(e1bf + rowbase);
            const short8 a1 = *(const short8*)(e1bf + rowbase + 32);
            f32x4 c[4];
#pragma unroll
            for (int t = 0; t < 4; t++) {
                c[t] = f32x4{0.f, 0.f, 0.f, 0.f};
                c[t] = __builtin_amdgcn_mfma_f32_16x16x32_bf16(a0, bfr[t][0], c[t], 0, 0, 0);
                c[t] = __builtin_amdgcn_mfma_f32_16x16x32_bf16(a1, bfr[t][1], c[t], 0, 0, 0);
            }
#pragma unroll
            for (int t = 0; t < 4; t++)
#pragma unroll
                for (int j = 0; j < 4; j++)
                    rb1 += tanh_fast(c[t][j] + fb[t]) * fu[t];
        }
    }
    const float b0 = wave_sum(rb0);
    const float b1 = wave_sum(rb1);
    if (lane == 0) { atomicAdd(&s_part[0], b0); atomicAdd(&s_part[1], b1); }
    __syncthreads();
    if (tid == 0) {
        bpart[blockIdx.x]             = s_part[0];
        bpart[BETA_GRID + blockIdx.x] = s_part[1];
    }
}

// Kernel 3.5: single-block reduction of all partials -> accum.
__global__ __launch_bounds__(256) void k_reduce(
    const float* __restrict__ part, const float* __restrict__ bpart,
    float* __restrict__ accum)
{
    const int tid = threadIdx.x, lane = tid & 63, wid = tid >> 6;
    if (wid == 0) {
        float t0 = 0.f, t1 = 0.f;
#pragma unroll
        for (int k = 0; k < BETA_GRID / 64; k++) {
            t0 += bpart[lane + 64 * k];
            t1 += bpart[BETA_GRID + lane + 64 * k];
        }
        t0 = wave_sum(t0); t1 = wave_sum(t1);
        if (lane == 0) { accum[0] = t0; accum[1] = t1; }
    }
    for (int j = wid; j < 65; j += 4) {
        float s = 0.f;
#pragma unroll
        for (int k = 0; k < PROJ_GRID / 64; k++)
            s += part[j * PROJ_GRID + lane + 64 * k];
        s = wave_sum(s);
        if (lane == 0) {
            if (j < 64) accum[4 + j] = s;
            else        accum[2] = s;
        }
    }
}

// Kernel 4: final elementwise combine.
__global__ __launch_bounds__(256) void k_out(
    const unsigned short* __restrict__ e0bf, const unsigned short* __restrict__ e1bf,
    const float* __restrict__ accum, const float* __restrict__ gate,
    float* __restrict__ out)
{
    const int i = blockIdx.x * 256 + threadIdx.x;
    const float b0 = accum[0] * (1.f / N_NODES);
    const float b1 = accum[1] * (1.f / N_NODES);
    const float mx = fmaxf(b0, b1);
    const float eb0 = __expf(b0 - mx), eb1 = __expf(b1 - mx);
    const float gv  = 1.f / (1.f + __expf(-gate[0]));
    const float c0  = gv * eb0 / (eb0 + eb1);
    const float c1  = gv * eb1 / (eb0 + eb1);
    const float cg  = (1.f - gv) / accum[2];

    const float4 av = ((const float4*)(accum + 4))[i & 15];
    const ushort4 ua = ((const ushort4*)e0bf)[i];
    const ushort4 ub = ((const ushort4*)e1bf)[i];
    float4 o;
    o.x = c0 * bf2f(ua.x) + c1 * bf2f(ub.x) + cg * av.x;
    o.y = c0 * bf2f(ua.y) + c1 * bf2f(ub.y) + cg * av.y;
    o.z = c0 * bf2f(ua.z) + c1 * bf2f(ub.z) + cg * av.z;
    o.w = c0 * bf2f(ua.w) + c1 * bf2f(ub.w) + cg * av.w;
    ((float4*)out)[i] = o;
}

extern "C" void kernel_launch(void* const* d_in, const int* in_sizes, int n_in,
                              void* d_out, int out_size, void* d_ws, size_t ws_size,
                              hipStream_t stream) {
    (void)in_sizes; (void)n_in; (void)out_size; (void)ws_size;
    const float* h0   = (const float*)d_in[0];
    const float* h1   = (const float*)d_in[1];
    const float* h2   = (const float*)d_in[2];
    const int*   nei0 = (const int*)  d_in[3];
    const int*   nei1 = (const int*)  d_in[4];
    const float* aw0  = (const float*)d_in[5];
    const float* aw1  = (const float*)d_in[6];
    const float* fcw  = (const float*)d_in[7];
    const float* fcb  = (const float*)d_in[8];
    const float* fus  = (const float*)d_in[9];
    const float* gatt = (const float*)d_in[10];
    const float* gate = (const float*)d_in[11];
    float* out = (float*)d_out;

    float* ws    = (float*)d_ws;
    float* accum = ws;                               // [0]=b0 [1]=b1 [2]=sumexp [4..67]=wsum
    float* p0r0  = ws + 256;                         // N
    float* p0r1  = p0r0 + N_NODES;                   // N
    float* p1    = p0r1 + N_NODES;                   // M1  (p2 MUST follow p1: unified table)
    float* p2    = p1 + M1_N;                        // M2
    unsigned short* h1bf = (unsigned short*)(p2 + M2_N);            // M1*64 bf16 (h2bf follows)
    unsigned short* h2bf = h1bf + (size_t)M1_N * DD;                // M2*64 bf16
    unsigned short* e0bf = h2bf + (size_t)M2_N * DD;                // N*64 bf16
    unsigned short* e1bf = e0bf + (size_t)N_NODES * DD;             // N*64 bf16
    float* part  = (float*)(e1bf + (size_t)N_NODES * DD);           // 65*PROJ_GRID
    float* bpart = part + 65 * PROJ_GRID;                           // 2*BETA_GRID

    k_proj<<<PROJ_GRID, 256, 0, stream>>>(h0, h1, h2, aw0, aw1, gatt, part,
                                          p0r0, p0r1, p1, p2, h1bf, h2bf);
    k_attn<<<2048, 256, 0, stream>>>(h1bf, nei0, nei1, p0r0, p0r1, p1, e0bf, e1bf);
    k_beta<<<BETA_GRID, 256, 0, stream>>>(e0bf, e1bf, fcw, fcb, fus, bpart);
    k_reduce<<<1, 256, 0, stream>>>(part, bpart, accum);
    k_out<<<(N_NODES * DD / 4) / 256, 256, 0, stream>>>(e0bf, e1bf, accum, gate, out);
}

// Round 11
// 175.610 us; speedup vs baseline: 1.0390x; 1.0390x over previous
//
#include <hip/hip_runtime.h>
#include <math.h>

#define N_NODES 60000
#define M1_N    40000
#define M2_N    40000
#define DD      64
#define S0_N    10
#define S1_N    20
#define R_TOTAL (N_NODES + M1_N + M2_N)
#define T_H0    (N_NODES / 16)              // 3750 tiles
#define T_H1    (T_H0 + M1_N / 16)          // 6250
#define T_ALL   (T_H1 + M2_N / 16)          // 8750
#define PROJ_GRID 1024                      // must equal k_proj launch grid
#define BETA_GRID 512                       // must equal k_beta launch grid

typedef __attribute__((ext_vector_type(8))) short short8;   // 8 bf16 = 4 VGPRs
typedef __attribute__((ext_vector_type(4))) float f32x4;

__device__ __forceinline__ float wave_sum(float x) {
#pragma unroll
    for (int o = 32; o >= 1; o >>= 1) x += __shfl_xor(x, o, 64);
    return x;
}
__device__ __forceinline__ float bcast(float v, int l) {
    return __uint_as_float(__builtin_amdgcn_readlane(__float_as_uint(v), l));
}
__device__ __forceinline__ float tanh_fast(float x) {
    return 1.f - 2.f / (__expf(2.f * x) + 1.f);
}
// f32 -> bf16 round-to-nearest-even
__device__ __forceinline__ unsigned short f2bf(float x) {
    unsigned u = __float_as_uint(x);
    return (unsigned short)((u + 0x7FFFu + ((u >> 16) & 1u)) >> 16);
}
__device__ __forceinline__ float bf2f(unsigned short u) {
    return __uint_as_float(((unsigned)u) << 16);
}
__device__ __forceinline__ float elu(float x) {
    return (x > 0.f) ? x : (__expf(x) - 1.f);
}

// Kernel 1: projections + global softmax via MFMA. One wave = 16-row tile.
// Round-11: 2-stage SW pipeline — next tile's 4 float4 loads issued before
// current tile's convert/MFMA/transpose (hides streaming-load latency).
__global__ __launch_bounds__(256) void k_proj(
    const float* __restrict__ h0, const float* __restrict__ h1, const float* __restrict__ h2,
    const float* __restrict__ aw0, const float* __restrict__ aw1, const float* __restrict__ gatt,
    float* __restrict__ part,
    float* __restrict__ p0r0, float* __restrict__ p0r1,
    float* __restrict__ p1, float* __restrict__ p2,
    unsigned short* __restrict__ h1bf, unsigned short* __restrict__ h2bf)
{
    __shared__ float s_wsum[64];
    __shared__ float s_se;
    __shared__ float s_es[4][16];
    const int tid = threadIdx.x, lane = tid & 63, wid = tid >> 6;
    if (tid < 64) s_wsum[tid] = 0.f;
    if (tid == 0) s_se = 0.f;
    __syncthreads();

    const int m = lane & 15, quad = lane >> 4;

    // B-frag: col n = m; k = quad*8+j (half0) / 32+quad*8+j (half1)
    short8 b0, b1;
    {
        const float* vsel = 0;
        if (m == 1) vsel = aw0;
        else if (m == 2) vsel = aw1;
        else if (m == 3) vsel = aw0 + DD;
        else if (m == 4) vsel = aw1 + DD;
        else if (m == 0) vsel = gatt;
#pragma unroll
        for (int j = 0; j < 8; j++) {
            b0[j] = vsel ? (short)f2bf(vsel[quad * 8 + j]) : (short)0;
            b1[j] = vsel ? (short)f2bf(vsel[32 + quad * 8 + j]) : (short)0;
        }
    }

    float wacc0[8], wacc1[8];
#pragma unroll
    for (int j = 0; j < 8; j++) { wacc0[j] = 0.f; wacc1[j] = 0.f; }
    float r_se = 0.f;

    const int gw = blockIdx.x * 4 + wid, nw = gridDim.x * 4;

    int tile = gw;
    bool have = (tile < T_ALL);
    float4 va, vb, vc, vd;
    int rbase = 0, region = 0;
    if (have) {
        const float* src;
        if (tile < T_H0)      { src = h0; rbase = tile * 16;          region = 0; }
        else if (tile < T_H1) { src = h1; rbase = (tile - T_H0) * 16; region = 1; }
        else                  { src = h2; rbase = (tile - T_H1) * 16; region = 2; }
        const int row = rbase + m;
        const float4* rpa = (const float4*)(src + (size_t)row * DD + quad * 8);
        const float4* rpb = (const float4*)(src + (size_t)row * DD + 32 + quad * 8);
        va = rpa[0]; vb = rpa[1]; vc = rpb[0]; vd = rpb[1];
    }
    while (have) {
        const float4 xa = va, xb = vb, xc = vc, xd = vd;
        const int rb = rbase, rg = region;
        tile += nw; have = (tile < T_ALL);
        if (have) {   // prefetch next tile's rows (uniform branch; loads in flight)
            const float* src;
            if (tile < T_H0)      { src = h0; rbase = tile * 16;          region = 0; }
            else if (tile < T_H1) { src = h1; rbase = (tile - T_H0) * 16; region = 1; }
            else                  { src = h2; rbase = (tile - T_H1) * 16; region = 2; }
            const int row = rbase + m;
            const float4* rpa = (const float4*)(src + (size_t)row * DD + quad * 8);
            const float4* rpb = (const float4*)(src + (size_t)row * DD + 32 + quad * 8);
            va = rpa[0]; vb = rpa[1]; vc = rpb[0]; vd = rpb[1];
        }

        short8 a0, a1;
        a0[0] = (short)f2bf(xa.x); a0[1] = (short)f2bf(xa.y);
        a0[2] = (short)f2bf(xa.z); a0[3] = (short)f2bf(xa.w);
        a0[4] = (short)f2bf(xb.x); a0[5] = (short)f2bf(xb.y);
        a0[6] = (short)f2bf(xb.z); a0[7] = (short)f2bf(xb.w);
        a1[0] = (short)f2bf(xc.x); a1[1] = (short)f2bf(xc.y);
        a1[2] = (short)f2bf(xc.z); a1[3] = (short)f2bf(xc.w);
        a1[4] = (short)f2bf(xd.x); a1[5] = (short)f2bf(xd.y);
        a1[6] = (short)f2bf(xd.z); a1[7] = (short)f2bf(xd.w);

        f32x4 c = {0.f, 0.f, 0.f, 0.f};
        c = __builtin_amdgcn_mfma_f32_16x16x32_bf16(a0, b0, c, 0, 0, 0);
        c = __builtin_amdgcn_mfma_f32_16x16x32_bf16(a1, b1, c, 0, 0, 0);
        // D[row=quad*4+r][col=m]

        if (m == 0) {        // global-att scores -> es, transposed via LDS
            float4 e4;
            e4.x = __expf(c[0] * 0.125f); e4.y = __expf(c[1] * 0.125f);
            e4.z = __expf(c[2] * 0.125f); e4.w = __expf(c[3] * 0.125f);
            *(float4*)&s_es[wid][quad * 4] = e4;
        }
        __builtin_amdgcn_wave_barrier();   // in-order DS pipe: same-wave write->read safe
        const float es = s_es[wid][m];     // es for this lane's row m
        r_se += es;                         // counted 4x (quads); scaled below
        wacc0[0] = fmaf(es, xa.x, wacc0[0]); wacc0[1] = fmaf(es, xa.y, wacc0[1]);
        wacc0[2] = fmaf(es, xa.z, wacc0[2]); wacc0[3] = fmaf(es, xa.w, wacc0[3]);
        wacc0[4] = fmaf(es, xb.x, wacc0[4]); wacc0[5] = fmaf(es, xb.y, wacc0[5]);
        wacc0[6] = fmaf(es, xb.z, wacc0[6]); wacc0[7] = fmaf(es, xb.w, wacc0[7]);
        wacc1[0] = fmaf(es, xc.x, wacc1[0]); wacc1[1] = fmaf(es, xc.y, wacc1[1]);
        wacc1[2] = fmaf(es, xc.z, wacc1[2]); wacc1[3] = fmaf(es, xc.w, wacc1[3]);
        wacc1[4] = fmaf(es, xd.x, wacc1[4]); wacc1[5] = fmaf(es, xd.y, wacc1[5]);
        wacc1[6] = fmaf(es, xd.z, wacc1[6]); wacc1[7] = fmaf(es, xd.w, wacc1[7]);

        const int row = rb + m;
        if (rg == 0) {
            if (m == 1) { float4 t = {c[0], c[1], c[2], c[3]}; *(float4*)(p0r0 + rb + quad * 4) = t; }
            if (m == 2) { float4 t = {c[0], c[1], c[2], c[3]}; *(float4*)(p0r1 + rb + quad * 4) = t; }
        } else if (rg == 1) {
            if (m == 3) { float4 t = {c[0], c[1], c[2], c[3]}; *(float4*)(p1 + rb + quad * 4) = t; }
            *(short8*)(h1bf + (size_t)row * DD + quad * 8) = a0;
            *(short8*)(h1bf + (size_t)row * DD + 32 + quad * 8) = a1;
        } else {
            if (m == 4) { float4 t = {c[0], c[1], c[2], c[3]}; *(float4*)(p2 + rb + quad * 4) = t; }
            *(short8*)(h2bf + (size_t)row * DD + quad * 8) = a0;
            *(short8*)(h2bf + (size_t)row * DD + 32 + quad * 8) = a1;
        }
    }

    r_se *= 0.25f;
#pragma unroll
    for (int o = 1; o <= 8; o <<= 1) {
#pragma unroll
        for (int j = 0; j < 8; j++) {
            wacc0[j] += __shfl_xor(wacc0[j], o, 64);
            wacc1[j] += __shfl_xor(wacc1[j], o, 64);
        }
    }
    if (m == 0) {
#pragma unroll
        for (int j = 0; j < 8; j++) {
            atomicAdd(&s_wsum[quad * 8 + j],      wacc0[j]);   // LDS atomic: cheap
            atomicAdd(&s_wsum[32 + quad * 8 + j], wacc1[j]);
        }
    }
    const float se = wave_sum(r_se);
    if (lane == 0) atomicAdd(&s_se, se);
    __syncthreads();
    if (tid < 64) part[tid * PROJ_GRID + blockIdx.x] = s_wsum[tid];
    if (tid == 64) part[64 * PROJ_GRID + blockIdx.x] = s_se;
}

// Kernel 2: neighbor attention — round-8 geometry (proven 45.5 µs) +
// 2-stage SW pipeline: next node's stage-1 loads (nei idx, p1 gather, p0r)
// issued before this node's row-gathers/butterflies, overlapping the
// ~400-600 cyc chain front with the current node's back half.
__global__ __launch_bounds__(256) void k_attn(
    const unsigned short* __restrict__ h1bf,
    const int* __restrict__ nei0, const int* __restrict__ nei1,
    const float* __restrict__ p0r0, const float* __restrict__ p0r1,
    const float* __restrict__ p1,
    unsigned short* __restrict__ e0bf, unsigned short* __restrict__ e1bf)
{
    const int tid = threadIdx.x, lane = tid & 63, wid = tid >> 6;
    const int sub = lane & 15, grp = lane >> 4;
    const bool grp0 = (lane < S0_N);
    const bool grp1 = (lane >= 32) && (lane < 32 + S1_N);
    const int gw = blockIdx.x * 4 + wid;
    const int nw = gridDim.x * 4;

    int n = gw;
    bool have = (n < N_NODES);
    int idx_c = 0; float pv_c = 0.f, pr_c = 0.f;
    if (have) {
        if (grp0) idx_c = nei0[n * S0_N + lane];
        if (grp1) idx_c = nei1[n * S1_N + (lane - 32)] + M1_N;   // unified table
        if (grp0 | grp1) pv_c = p1[idx_c];
        pr_c = (lane < 32) ? p0r0[n] : p0r1[n];
    }
    while (have) {
        const int idx = idx_c;
        const float pv = pv_c, pr = pr_c;
        const int ncur = n;
        n += nw; have = (n < N_NODES);
        if (have) {                       // stage-1 prefetch for next node
            int ix = 0;
            if (grp0) ix = nei0[n * S0_N + lane];
            if (grp1) ix = nei1[n * S1_N + (lane - 32)] + M1_N;
            idx_c = ix;
            if (grp0 | grp1) pv_c = p1[ix];
            pr_c = (lane < 32) ? p0r0[n] : p0r1[n];
        }

        float w = 0.f;
        if (grp0 | grp1) {
            float sc = pr + pv;
            sc = (sc >= 0.f) ? sc : 0.01f * sc;      // leaky_relu(0.01)
            w = __expf(sc);                           // bounded; no max-sub
        }

        // rows for this group's slice of each 4-row gather (invalid slots
        // 10,11 of the e0 3x4 grid carry idx=0,w=0 -> harmless)
        int r0[3], r1[5];
#pragma unroll
        for (int j = 0; j < 3; j++) r0[j] = __shfl(idx, 4 * j + grp, 64);
#pragma unroll
        for (int j = 0; j < 5; j++) r1[j] = __shfl(idx, 32 + 4 * j + grp, 64);

        // issue all 8 gathers (512 B each) before the softmax butterfly
        ushort4 u0[3], u1[5];
#pragma unroll
        for (int j = 0; j < 3; j++)
            u0[j] = *(const ushort4*)(h1bf + r0[j] * DD + 4 * sub);
#pragma unroll
        for (int j = 0; j < 5; j++)
            u1[j] = *(const ushort4*)(h1bf + r1[j] * DD + 4 * sub);

        float sv = w;
#pragma unroll
        for (int o = 16; o >= 1; o >>= 1) sv += __shfl_xor(sv, o, 64);
        const float inv0 = 1.f / bcast(sv, 0);
        const float inv1 = 1.f / bcast(sv, 32);

        float w0[3], w1[5];
#pragma unroll
        for (int j = 0; j < 3; j++) w0[j] = __shfl(w, 4 * j + grp, 64);
#pragma unroll
        for (int j = 0; j < 5; j++) w1[j] = __shfl(w, 32 + 4 * j + grp, 64);

        float4 a0 = make_float4(0.f, 0.f, 0.f, 0.f);
#pragma unroll
        for (int j = 0; j < 3; j++) {
            a0.x = fmaf(w0[j], bf2f(u0[j].x), a0.x);
            a0.y = fmaf(w0[j], bf2f(u0[j].y), a0.y);
            a0.z = fmaf(w0[j], bf2f(u0[j].z), a0.z);
            a0.w = fmaf(w0[j], bf2f(u0[j].w), a0.w);
        }
        float4 a1 = make_float4(0.f, 0.f, 0.f, 0.f);
#pragma unroll
        for (int j = 0; j < 5; j++) {
            a1.x = fmaf(w1[j], bf2f(u1[j].x), a1.x);
            a1.y = fmaf(w1[j], bf2f(u1[j].y), a1.y);
            a1.z = fmaf(w1[j], bf2f(u1[j].z), a1.z);
            a1.w = fmaf(w1[j], bf2f(u1[j].w), a1.w);
        }
        // merge the 4 groups (each holds a disjoint neighbor subset, same dims)
#pragma unroll
        for (int o = 16; o <= 32; o <<= 1) {
            a0.x += __shfl_xor(a0.x, o, 64); a0.y += __shfl_xor(a0.y, o, 64);
            a0.z += __shfl_xor(a0.z, o, 64); a0.w += __shfl_xor(a0.w, o, 64);
            a1.x += __shfl_xor(a1.x, o, 64); a1.y += __shfl_xor(a1.y, o, 64);
            a1.z += __shfl_xor(a1.z, o, 64); a1.w += __shfl_xor(a1.w, o, 64);
        }
        if (grp == 0) {
            ushort4 s;
            s.x = f2bf(elu(a0.x * inv0)); s.y = f2bf(elu(a0.y * inv0));
            s.z = f2bf(elu(a0.z * inv0)); s.w = f2bf(elu(a0.w * inv0));
            *(ushort4*)(e0bf + ncur * DD + 4 * sub) = s;
        } else if (grp == 1) {
            ushort4 s;
            s.x = f2bf(elu(a1.x * inv1)); s.y = f2bf(elu(a1.y * inv1));
            s.z = f2bf(elu(a1.z * inv1)); s.w = f2bf(elu(a1.w * inv1));
            *(ushort4*)(e1bf + ncur * DD + 4 * sub) = s;
        }
    }
}

// Kernel 3: beta reduction via MFMA; per-block partial stores.
__global__ __launch_bounds__(256) void k_beta(
    const unsigned short* __restrict__ e0bf, const unsigned short* __restrict__ e1bf,
    const float* __restrict__ fcw, const float* __restrict__ fcb,
    const float* __restrict__ fus, float* __restrict__ bpart)
{
    __shared__ float s_part[2];
    const int tid = threadIdx.x, lane = tid & 63, wid = tid >> 6;
    if (tid < 2) s_part[tid] = 0.f;
    const int m = lane & 15, q = lane >> 4;

    short8 bfr[4][2];
    float fb[4], fu[4];
#pragma unroll
    for (int t = 0; t < 4; t++) {
        const float* wrow = fcw + (t * 16 + m) * DD;
#pragma unroll
        for (int h = 0; h < 2; h++) {
            const float* p = wrow + h * 32 + q * 8;
#pragma unroll
            for (int j = 0; j < 8; j++) bfr[t][h][j] = (short)f2bf(p[j]);
        }
        fb[t] = fcb[t * 16 + m];
        fu[t] = fus[t * 16 + m];
    }
    __syncthreads();

    float rb0 = 0.f, rb1 = 0.f;
    const int gw = blockIdx.x * 4 + wid;
    const int nw = gridDim.x * 4;
    for (int tile = gw; tile < N_NODES / 16; tile += nw) {
        const int rowbase = (tile * 16 + m) * DD + q * 8;
        {
            const short8 a0 = *(const short8*)(e0bf + rowbase);
            const short8 a1 = *(const short8*)(e0bf + rowbase + 32);
            f32x4 c[4];
#pragma unroll
            for (int t = 0; t < 4; t++) {
                c[t] = f32x4{0.f, 0.f, 0.f, 0.f};
                c[t] = __builtin_amdgcn_mfma_f32_16x16x32_bf16(a0, bfr[t][0], c[t], 0, 0, 0);
                c[t] = __builtin_amdgcn_mfma_f32_16x16x32_bf16(a1, bfr[t][1], c[t], 0, 0, 0);
            }
#pragma unroll
            for (int t = 0; t < 4; t++)
#pragma unroll
                for (int j = 0; j < 4; j++)
                    rb0 += tanh_fast(c[t][j] + fb[t]) * fu[t];
        }
        {
            const short8 a0 = *(const short8*)(e1bf + rowbase);
            const short8 a1 = *(const short8*)(e1bf + rowbase + 32);
            f32x4 c[4];
#pragma unroll
            for (int t = 0; t < 4; t++) {
                c[t] = f32x4{0.f, 0.f, 0.f, 0.f};
                c[t] = __builtin_amdgcn_mfma_f32_16x16x32_bf16(a0, bfr[t][0], c[t], 0, 0, 0);
                c[t] = __builtin_amdgcn_mfma_f32_16x16x32_bf16(a1, bfr[t][1], c[t], 0, 0, 0);
            }
#pragma unroll
            for (int t = 0; t < 4; t++)
#pragma unroll
                for (int j = 0; j < 4; j++)
                    rb1 += tanh_fast(c[t][j] + fb[t]) * fu[t];
        }
    }
    const float b0 = wave_sum(rb0);
    const float b1 = wave_sum(rb1);
    if (lane == 0) { atomicAdd(&s_part[0], b0); atomicAdd(&s_part[1], b1); }   // LDS
    __syncthreads();
    if (tid == 0) {
        bpart[blockIdx.x]             = s_part[0];
        bpart[BETA_GRID + blockIdx.x] = s_part[1];
    }
}

// Kernel 3.5: single-block reduction of all partials -> accum.
__global__ __launch_bounds__(256) void k_reduce(
    const float* __restrict__ part, const float* __restrict__ bpart,
    float* __restrict__ accum)
{
    const int tid = threadIdx.x, lane = tid & 63, wid = tid >> 6;
    if (wid == 0) {
        float t0 = 0.f, t1 = 0.f;
#pragma unroll
        for (int k = 0; k < BETA_GRID / 64; k++) {
            t0 += bpart[lane + 64 * k];
            t1 += bpart[BETA_GRID + lane + 64 * k];
        }
        t0 = wave_sum(t0); t1 = wave_sum(t1);
        if (lane == 0) { accum[0] = t0; accum[1] = t1; }
    }
    for (int j = wid; j < 65; j += 4) {
        float s = 0.f;
#pragma unroll
        for (int k = 0; k < PROJ_GRID / 64; k++)
            s += part[j * PROJ_GRID + lane + 64 * k];
        s = wave_sum(s);
        if (lane == 0) {
            if (j < 64) accum[4 + j] = s;
            else        accum[2] = s;
        }
    }
}

// Kernel 4: final elementwise combine.
__global__ __launch_bounds__(256) void k_out(
    const unsigned short* __restrict__ e0bf, const unsigned short* __restrict__ e1bf,
    const float* __restrict__ accum, const float* __restrict__ gate,
    float* __restrict__ out)
{
    const int i = blockIdx.x * 256 + threadIdx.x;
    const float b0 = accum[0] * (1.f / N_NODES);
    const float b1 = accum[1] * (1.f / N_NODES);
    const float mx = fmaxf(b0, b1);
    const float eb0 = __expf(b0 - mx), eb1 = __expf(b1 - mx);
    const float gv  = 1.f / (1.f + __expf(-gate[0]));
    const float c0  = gv * eb0 / (eb0 + eb1);
    const float c1  = gv * eb1 / (eb0 + eb1);
    const float cg  = (1.f - gv) / accum[2];

    const float4 av = ((const float4*)(accum + 4))[i & 15];
    const ushort4 ua = ((const ushort4*)e0bf)[i];
    const ushort4 ub = ((const ushort4*)e1bf)[i];
    float4 o;
    o.x = c0 * bf2f(ua.x) + c1 * bf2f(ub.x) + cg * av.x;
    o.y = c0 * bf2f(ua.y) + c1 * bf2f(ub.y) + cg * av.y;
    o.z = c0 * bf2f(ua.z) + c1 * bf2f(ub.z) + cg * av.z;
    o.w = c0 * bf2f(ua.w) + c1 * bf2f(ub.w) + cg * av.w;
    ((float4*)out)[i] = o;
}

extern "C" void kernel_launch(void* const* d_in, const int* in_sizes, int n_in,
                              void* d_out, int out_size, void* d_ws, size_t ws_size,
                              hipStream_t stream) {
    (void)in_sizes; (void)n_in; (void)out_size; (void)ws_size;
    const float* h0   = (const float*)d_in[0];
    const float* h1   = (const float*)d_in[1];
    const float* h2   = (const float*)d_in[2];
    const int*   nei0 = (const int*)  d_in[3];
    const int*   nei1 = (const int*)  d_in[4];
    const float* aw0  = (const float*)d_in[5];
    const float* aw1  = (const float*)d_in[6];
    const float* fcw  = (const float*)d_in[7];
    const float* fcb  = (const float*)d_in[8];
    const float* fus  = (const float*)d_in[9];
    const float* gatt = (const float*)d_in[10];
    const float* gate = (const float*)d_in[11];
    float* out = (float*)d_out;

    float* ws    = (float*)d_ws;
    float* accum = ws;                               // [0]=b0 [1]=b1 [2]=sumexp [4..67]=wsum
    float* p0r0  = ws + 256;                         // N
    float* p0r1  = p0r0 + N_NODES;                   // N
    float* p1    = p0r1 + N_NODES;                   // M1  (p2 MUST follow p1: unified table)
    float* p2    = p1 + M1_N;                        // M2
    unsigned short* h1bf = (unsigned short*)(p2 + M2_N);            // M1*64 bf16 (h2bf follows)
    unsigned short* h2bf = h1bf + (size_t)M1_N * DD;                // M2*64 bf16
    unsigned short* e0bf = h2bf + (size_t)M2_N * DD;                // N*64 bf16
    unsigned short* e1bf = e0bf + (size_t)N_NODES * DD;             // N*64 bf16
    float* part  = (float*)(e1bf + (size_t)N_NODES * DD);           // 65*PROJ_GRID
    float* bpart = part + 65 * PROJ_GRID;                           // 2*BETA_GRID

    k_proj<<<PROJ_GRID, 256, 0, stream>>>(h0, h1, h2, aw0, aw1, gatt, part,
                                          p0r0, p0r1, p1, p2, h1bf, h2bf);
    k_attn<<<2048, 256, 0, stream>>>(h1bf, nei0, nei1, p0r0, p0r1, p1, e0bf, e1bf);
    k_beta<<<BETA_GRID, 256, 0, stream>>>(e0bf, e1bf, fcw, fcb, fus, bpart);
    k_reduce<<<1, 256, 0, stream>>>(part, bpart, accum);
    k_out<<<(N_NODES * DD / 4) / 256, 256, 0, stream>>>(e0bf, e1bf, accum, gate, out);
}